// Round 7
// baseline (628.304 us; speedup 1.0000x reference)
//
#include <hip/hip_runtime.h>
#include <math.h>

// Problem constants (from reference setup_inputs)
#define NB      32      // batch
#define NKV     8       // kv heads
#define NQ      32      // query heads
#define GQ      4       // GQA group size = NQ/NKV
#define DH      128     // head dim
#define TPP     16      // tokens per page
#define PPS     128     // pages per slot
#define NPAGES  4096    // total pages
#define NSPLIT  16      // S-splits per (b,kv)
#define NBK     (NB*NKV)        // 256 (b,kv) pairs
#define PAGE_F  (TPP*DH)        // floats per page = 2048
#define PART_F  (GQ*DH + 2*GQ)  // partial size: o[4][128] + m[4] + l[4] = 520
#define WS_PART_FLOATS ((size_t)NBK * NSPLIT * PART_F)

// ---------------------------------------------------------------------------
// Fused single-pass paged attention (flash-decoding with last-block combine).
// Block = (b, kv, sp). Each 16-lane group owns token slot `grp` of every page
// p = sp, sp+NSPLIT, ... with its own in-register online softmax; K/V stream
// global->register with 1-page data prefetch and 2-page page-INDEX prefetch
// (decouples the pmap->address dependency from the KV latency). After the
// block-level merge, the partial goes to ws; the LAST split block to arrive
// for its (b,kv) (atomic counter) performs the LSE combine and writes out.
// ---------------------------------------------------------------------------
__global__ __launch_bounds__(256) void pa_fused(
    const float* __restrict__ query,
    const float* __restrict__ key_pages,
    const float* __restrict__ value_pages,
    const int*   __restrict__ page_map,
    const int*   __restrict__ seq_lengths,
    float*       __restrict__ ws,
    unsigned*    __restrict__ counters,
    float*       __restrict__ out)
{
    const int blk = blockIdx.x;          // (b*NKV + kv)*NSPLIT + sp
    const int sp  = blk & (NSPLIT - 1);
    const int bk  = blk >> 4;            // NSPLIT = 16
    const int kv  = bk & (NKV - 1);
    const int b   = bk >> 3;
    const int tid = threadIdx.x;

    const int seq     = seq_lengths[b];
    const int n_pages = (seq + TPP - 1) / TPP;
    const int ns      = (n_pages < NSPLIT) ? n_pages : NSPLIT;  // active splits
    if (sp >= n_pages) return;           // inactive split: never counted

    const int grp = tid >> 4;            // token slot 0..15 within a page
    const int l16 = tid & 15;            // lane within token group
    const int c0  = l16 * 4;             // chunk 0: floats [c0, c0+4)
    const int c1  = 64 + l16 * 4;        // chunk 1: floats [c1, c1+4)

    // Q fragments (d-slices of all 4 group heads, same mapping as K)
    float qreg[GQ][8];
    #pragma unroll
    for (int g = 0; g < GQ; ++g) {
        const float* qb = query + (size_t)((b * NQ + kv * GQ + g) * DH);
        const float4 a = *(const float4*)(qb + c0);
        const float4 c = *(const float4*)(qb + c1);
        qreg[g][0] = a.x; qreg[g][1] = a.y; qreg[g][2] = a.z; qreg[g][3] = a.w;
        qreg[g][4] = c.x; qreg[g][5] = c.y; qreg[g][6] = c.z; qreg[g][7] = c.w;
    }

    const float* kbase = key_pages   + (size_t)kv * NPAGES * PAGE_F;
    const float* vbase = value_pages + (size_t)kv * NPAGES * PAGE_F;
    const int*   pmap  = page_map + b * PPS;

    // per-group online softmax state (finite init keeps masked-only groups
    // NaN-free; their l stays 0 and the merge weight underflows to 0)
    float m[GQ] = {-1e30f, -1e30f, -1e30f, -1e30f};
    float l[GQ] = {0.f, 0.f, 0.f, 0.f};
    float acc[GQ][8] = {};

    // page-index prefetch (2 ahead) + data prefetch (1 ahead)
    int pg_nxt = (sp + NSPLIT < n_pages) ? pmap[sp + NSPLIT] : 0;
    float4 ck0, ck1, cv0, cv1;
    {
        const size_t ro = (size_t)pmap[sp] * PAGE_F + grp * DH;
        ck0 = *(const float4*)(kbase + ro + c0);
        ck1 = *(const float4*)(kbase + ro + c1);
        cv0 = *(const float4*)(vbase + ro + c0);
        cv1 = *(const float4*)(vbase + ro + c1);
    }

    for (int p = sp; p < n_pages; p += NSPLIT) {
        // issue next page's loads first; index was prefetched last iteration
        float4 nk0, nk1, nv0, nv1;
        const int pn = p + NSPLIT;
        if (pn < n_pages) {
            const size_t ro = (size_t)pg_nxt * PAGE_F + grp * DH;
            nk0 = *(const float4*)(kbase + ro + c0);
            nk1 = *(const float4*)(kbase + ro + c1);
            nv0 = *(const float4*)(vbase + ro + c0);
            nv1 = *(const float4*)(vbase + ro + c1);
            pg_nxt = (pn + NSPLIT < n_pages) ? pmap[pn + NSPLIT] : 0;
        }

        // ---- scores: s[g] = q[g] . K[grp]  (reduce across 16 lanes) ----
        const float kx[8] = {ck0.x, ck0.y, ck0.z, ck0.w, ck1.x, ck1.y, ck1.z, ck1.w};
        float s[GQ];
        #pragma unroll
        for (int g = 0; g < GQ; ++g) {
            float t = qreg[g][0]*kx[0] + qreg[g][1]*kx[1] + qreg[g][2]*kx[2] + qreg[g][3]*kx[3]
                    + qreg[g][4]*kx[4] + qreg[g][5]*kx[5] + qreg[g][6]*kx[6] + qreg[g][7]*kx[7];
            #pragma unroll
            for (int off = 8; off >= 1; off >>= 1) t += __shfl_xor(t, off);
            s[g] = t;
        }

        const bool valid = (p * TPP + grp) < seq;
        const float vx[8] = {cv0.x, cv0.y, cv0.z, cv0.w, cv1.x, cv1.y, cv1.z, cv1.w};

        // ---- per-group online softmax update (single token) ----
        #pragma unroll
        for (int g = 0; g < GQ; ++g) {
            const float mn = fmaxf(m[g], s[g]);
            float pc = __expf(s[g] - mn);
            pc = valid ? pc : 0.f;
            const float sc = __expf(m[g] - mn);
            m[g] = mn;
            l[g] = l[g] * sc + pc;
            #pragma unroll
            for (int j = 0; j < 8; ++j)
                acc[g][j] = acc[g][j] * sc + pc * vx[j];
        }

        ck0 = nk0; ck1 = nk1; cv0 = nv0; cv1 = nv1;   // SSA rename, free
    }

    // ---- block-level merge of the 16 group partials via LDS ----
    __shared__ float s_acc[16][GQ][DH];   // 32 KB
    __shared__ float s_m[16][GQ];
    __shared__ float s_l[16][GQ];
    __shared__ unsigned s_old;

    #pragma unroll
    for (int g = 0; g < GQ; ++g) {
        *(float4*)&s_acc[grp][g][c0] = make_float4(acc[g][0], acc[g][1], acc[g][2], acc[g][3]);
        *(float4*)&s_acc[grp][g][c1] = make_float4(acc[g][4], acc[g][5], acc[g][6], acc[g][7]);
    }
    if (l16 == 0) {
        #pragma unroll
        for (int g = 0; g < GQ; ++g) { s_m[grp][g] = m[g]; s_l[grp][g] = l[g]; }
    }
    __syncthreads();

    // remap: thread -> (gA, d) and (gB, d)
    const int d  = tid & 127;
    const int gA = tid >> 7;     // 0 or 1
    const int gB = gA + 2;       // 2 or 3

    float MA = -1e30f, MB = -1e30f;
    #pragma unroll
    for (int i = 0; i < 16; ++i) {
        MA = fmaxf(MA, s_m[i][gA]);
        MB = fmaxf(MB, s_m[i][gB]);
    }
    float LA = 0.f, LB = 0.f, oA = 0.f, oB = 0.f;
    #pragma unroll
    for (int i = 0; i < 16; ++i) {
        const float eA = __expf(s_m[i][gA] - MA);
        const float eB = __expf(s_m[i][gB] - MB);
        LA += s_l[i][gA] * eA;
        LB += s_l[i][gB] * eB;
        oA += s_acc[i][gA][d] * eA;
        oB += s_acc[i][gB][d] * eB;
    }

    // ---- write split partial (o unnormalized, m, l) ----
    float* base = ws + (size_t)(bk * NSPLIT + sp) * PART_F;
    base[gA * DH + d] = oA;
    base[gB * DH + d] = oB;
    if (d == 0) {  // tid 0 writes g0,g2 ; tid 128 writes g1,g3
        base[GQ * DH + gA]      = MA;
        base[GQ * DH + GQ + gA] = LA;
        base[GQ * DH + gB]      = MB;
        base[GQ * DH + GQ + gB] = LB;
    }

    // ---- last-block combine (rocPRIM device-reduce arrival pattern) ----
    __threadfence();                     // release: partial visible device-wide
    __syncthreads();                     // all threads' writes + fences done
    if (tid == 0) s_old = atomicAdd(&counters[bk], 1u);
    __syncthreads();
    if (s_old != (unsigned)(ns - 1)) return;
    __threadfence();                     // acquire: don't read stale partials

    const float* base0 = ws + (size_t)bk * NSPLIT * PART_F;
    float cMA = -1e30f, cMB = -1e30f;
    for (int si = 0; si < ns; ++si) {
        const float* pp = base0 + si * PART_F;
        cMA = fmaxf(cMA, pp[GQ * DH + gA]);
        cMB = fmaxf(cMB, pp[GQ * DH + gB]);
    }
    float cLA = 0.f, cLB = 0.f, coA = 0.f, coB = 0.f;
    for (int si = 0; si < ns; ++si) {
        const float* pp = base0 + si * PART_F;
        const float eA = __expf(pp[GQ * DH + gA] - cMA);
        const float eB = __expf(pp[GQ * DH + gB] - cMB);
        cLA += pp[GQ * DH + GQ + gA] * eA;
        cLB += pp[GQ * DH + GQ + gB] * eB;
        coA += pp[gA * DH + d] * eA;
        coB += pp[gB * DH + d] * eB;
    }
    float* ob = out + (size_t)(b * NQ + kv * GQ) * DH;
    ob[gA * DH + d] = coA / cLA;
    ob[gB * DH + d] = coB / cLB;
}

// ---------------------------------------------------------------------------
extern "C" void kernel_launch(void* const* d_in, const int* in_sizes, int n_in,
                              void* d_out, int out_size, void* d_ws, size_t ws_size,
                              hipStream_t stream)
{
    const float* query       = (const float*)d_in[0];
    const float* key_pages   = (const float*)d_in[1];
    const float* value_pages = (const float*)d_in[2];
    const int*   page_map    = (const int*)d_in[3];
    const int*   seq_lengths = (const int*)d_in[4];
    float*       out         = (float*)d_out;
    float*       ws          = (float*)d_ws;

    // ws layout: [partials: NBK*NSPLIT*PART_F floats (~8.5 MB)] [counters: NBK u32]
    unsigned* counters = (unsigned*)(ws + WS_PART_FLOATS);

    // zero arrival counters each call (graph-capturable async memset)
    hipMemsetAsync(counters, 0, NBK * sizeof(unsigned), stream);

    pa_fused<<<NBK * NSPLIT, 256, 0, stream>>>(
        query, key_pages, value_pages, page_map, seq_lengths, ws, counters, out);
}

// Round 8
// 63.191 us; speedup vs baseline: 9.9430x; 9.9430x over previous
//
#include <hip/hip_runtime.h>
#include <math.h>

// Problem constants (from reference setup_inputs)
#define NB      32      // batch
#define NKV     8       // kv heads
#define NQ      32      // query heads
#define GQ      4       // GQA group size = NQ/NKV
#define DH      128     // head dim
#define TPP     16      // tokens per page
#define PPS     128     // pages per slot
#define NPAGES  4096    // total pages
#define NSPLIT  16      // S-splits per (b,kv)
#define NBK     (NB*NKV)        // 256 (b,kv) pairs
#define PAGE_F  (TPP*DH)        // floats per page = 2048
#define PART_F  (GQ*DH + 2*GQ)  // partial size: o[4][128] + m[4] + l[4] = 520

// ---------------------------------------------------------------------------
// Kernel 1: barrier-free streaming paged attention partial.
// Block = (b, kv, sp). Each 16-lane group owns token slot `grp` of every page
// p = sp, sp+NSPLIT, ... with its own in-register online softmax; K/V stream
// global->register with 1-page data prefetch + 2-page page-index prefetch.
// Group partials are merged INTRA-WAVE via shfl_xor (no LDS), then only the
// 4 wave partials go through an 8.4 KB LDS merge -> 6-7 blocks/CU instead of
// the 4 the old 33 KB merge buffer allowed (more TLP, better latency hiding).
// ---------------------------------------------------------------------------
__global__ __launch_bounds__(256) void pa_partial(
    const float* __restrict__ query,
    const float* __restrict__ key_pages,
    const float* __restrict__ value_pages,
    const int*   __restrict__ page_map,
    const int*   __restrict__ seq_lengths,
    float*       __restrict__ ws)
{
    const int blk = blockIdx.x;          // (b*NKV + kv)*NSPLIT + sp
    const int sp  = blk & (NSPLIT - 1);
    const int bk  = blk >> 4;            // NSPLIT = 16
    const int kv  = bk & (NKV - 1);
    const int b   = bk >> 3;
    const int tid = threadIdx.x;

    const int seq     = seq_lengths[b];
    const int n_pages = (seq + TPP - 1) / TPP;
    if (sp >= n_pages) return;           // combine kernel skips inactive splits

    const int grp = tid >> 4;            // token slot 0..15 within a page
    const int l16 = tid & 15;            // lane within token group
    const int c0  = l16 * 4;             // chunk 0: floats [c0, c0+4)
    const int c1  = 64 + l16 * 4;        // chunk 1: floats [c1, c1+4)

    // Q fragments (d-slices of all 4 group heads, same mapping as K)
    float qreg[GQ][8];
    #pragma unroll
    for (int g = 0; g < GQ; ++g) {
        const float* qb = query + (size_t)((b * NQ + kv * GQ + g) * DH);
        const float4 a = *(const float4*)(qb + c0);
        const float4 c = *(const float4*)(qb + c1);
        qreg[g][0] = a.x; qreg[g][1] = a.y; qreg[g][2] = a.z; qreg[g][3] = a.w;
        qreg[g][4] = c.x; qreg[g][5] = c.y; qreg[g][6] = c.z; qreg[g][7] = c.w;
    }

    const float* kbase = key_pages   + (size_t)kv * NPAGES * PAGE_F;
    const float* vbase = value_pages + (size_t)kv * NPAGES * PAGE_F;
    const int*   pmap  = page_map + b * PPS;

    // per-group online softmax state (finite init keeps masked-only groups
    // NaN-free; their l stays 0 and the merge weight underflows to 0)
    float m[GQ] = {-1e30f, -1e30f, -1e30f, -1e30f};
    float l[GQ] = {0.f, 0.f, 0.f, 0.f};
    float acc[GQ][8] = {};

    // page-index prefetch (2 ahead) + data prefetch (1 ahead)
    int pg_nxt = (sp + NSPLIT < n_pages) ? pmap[sp + NSPLIT] : 0;
    float4 ck0, ck1, cv0, cv1;
    {
        const size_t ro = (size_t)pmap[sp] * PAGE_F + grp * DH;
        ck0 = *(const float4*)(kbase + ro + c0);
        ck1 = *(const float4*)(kbase + ro + c1);
        cv0 = *(const float4*)(vbase + ro + c0);
        cv1 = *(const float4*)(vbase + ro + c1);
    }

    for (int p = sp; p < n_pages; p += NSPLIT) {
        // issue next page's loads first; index was prefetched last iteration
        float4 nk0, nk1, nv0, nv1;
        const int pn = p + NSPLIT;
        if (pn < n_pages) {
            const size_t ro = (size_t)pg_nxt * PAGE_F + grp * DH;
            nk0 = *(const float4*)(kbase + ro + c0);
            nk1 = *(const float4*)(kbase + ro + c1);
            nv0 = *(const float4*)(vbase + ro + c0);
            nv1 = *(const float4*)(vbase + ro + c1);
            pg_nxt = (pn + NSPLIT < n_pages) ? pmap[pn + NSPLIT] : 0;
        }

        // ---- scores: s[g] = q[g] . K[grp]  (reduce across 16 lanes) ----
        const float kx[8] = {ck0.x, ck0.y, ck0.z, ck0.w, ck1.x, ck1.y, ck1.z, ck1.w};
        float s[GQ];
        #pragma unroll
        for (int g = 0; g < GQ; ++g) {
            float t = qreg[g][0]*kx[0] + qreg[g][1]*kx[1] + qreg[g][2]*kx[2] + qreg[g][3]*kx[3]
                    + qreg[g][4]*kx[4] + qreg[g][5]*kx[5] + qreg[g][6]*kx[6] + qreg[g][7]*kx[7];
            #pragma unroll
            for (int off = 8; off >= 1; off >>= 1) t += __shfl_xor(t, off);
            s[g] = t;
        }

        const bool valid = (p * TPP + grp) < seq;
        const float vx[8] = {cv0.x, cv0.y, cv0.z, cv0.w, cv1.x, cv1.y, cv1.z, cv1.w};

        // ---- per-group online softmax update (single token) ----
        #pragma unroll
        for (int g = 0; g < GQ; ++g) {
            const float mn = fmaxf(m[g], s[g]);
            float pc = __expf(s[g] - mn);
            pc = valid ? pc : 0.f;
            const float sc = __expf(m[g] - mn);
            m[g] = mn;
            l[g] = l[g] * sc + pc;
            #pragma unroll
            for (int j = 0; j < 8; ++j)
                acc[g][j] = acc[g][j] * sc + pc * vx[j];
        }

        ck0 = nk0; ck1 = nk1; cv0 = nv0; cv1 = nv1;   // SSA rename, free
    }

    // ---- intra-wave merge: the 4 token-groups of this wave combine their
    // states via shfl_xor(16), shfl_xor(32). Partner lanes share the same
    // l16 -> same d-slice, so acc elements align. No LDS, ~100 VALU once. ----
    #pragma unroll
    for (int off = 16; off <= 32; off <<= 1) {
        #pragma unroll
        for (int g = 0; g < GQ; ++g) {
            const float om = __shfl_xor(m[g], off);
            const float ol = __shfl_xor(l[g], off);
            float oa[8];
            #pragma unroll
            for (int j = 0; j < 8; ++j) oa[j] = __shfl_xor(acc[g][j], off);
            const float M  = fmaxf(m[g], om);
            const float e1 = __expf(m[g] - M);
            const float e2 = __expf(om   - M);
            m[g] = M;
            l[g] = l[g] * e1 + ol * e2;
            #pragma unroll
            for (int j = 0; j < 8; ++j) acc[g][j] = acc[g][j] * e1 + oa[j] * e2;
        }
    }

    // ---- cross-wave merge via small LDS (4 wave-partials, 8.4 KB) ----
    __shared__ float s_acc[4][GQ][DH];   // 8 KB
    __shared__ float s_m[4][GQ];
    __shared__ float s_l[4][GQ];

    const int wv   = tid >> 6;
    const int lane = tid & 63;
    if (lane < 16) {                     // l16 == lane for these
        #pragma unroll
        for (int g = 0; g < GQ; ++g) {
            *(float4*)&s_acc[wv][g][c0] = make_float4(acc[g][0], acc[g][1], acc[g][2], acc[g][3]);
            *(float4*)&s_acc[wv][g][c1] = make_float4(acc[g][4], acc[g][5], acc[g][6], acc[g][7]);
        }
        if (lane == 0) {
            #pragma unroll
            for (int g = 0; g < GQ; ++g) { s_m[wv][g] = m[g]; s_l[wv][g] = l[g]; }
        }
    }
    __syncthreads();

    // remap: thread -> (gA, d) and (gB, d)
    const int d  = tid & 127;
    const int gA = tid >> 7;     // 0 or 1
    const int gB = gA + 2;       // 2 or 3

    float MA = -1e30f, MB = -1e30f;
    #pragma unroll
    for (int i = 0; i < 4; ++i) {
        MA = fmaxf(MA, s_m[i][gA]);
        MB = fmaxf(MB, s_m[i][gB]);
    }
    float LA = 0.f, LB = 0.f, oA = 0.f, oB = 0.f;
    #pragma unroll
    for (int i = 0; i < 4; ++i) {
        const float eA = __expf(s_m[i][gA] - MA);
        const float eB = __expf(s_m[i][gB] - MB);
        LA += s_l[i][gA] * eA;
        LB += s_l[i][gB] * eB;
        oA += s_acc[i][gA][d] * eA;
        oB += s_acc[i][gB][d] * eB;
    }

    // ---- write partial (o unnormalized, m, l); ws layout unchanged ----
    float* base = ws + (size_t)(bk * NSPLIT + sp) * PART_F;
    base[gA * DH + d] = oA;
    base[gB * DH + d] = oB;
    if (d == 0) {  // tid 0 writes g0,g2 ; tid 128 writes g1,g3
        base[GQ * DH + gA]      = MA;
        base[GQ * DH + GQ + gA] = LA;
        base[GQ * DH + gB]      = MB;
        base[GQ * DH + GQ + gB] = LB;
    }
}

// ---------------------------------------------------------------------------
// Kernel 2: combine the <=NSPLIT split partials per (b, kv), write output.
// ---------------------------------------------------------------------------
__global__ __launch_bounds__(256) void pa_combine(
    const float* __restrict__ ws,
    const int*   __restrict__ seq_lengths,
    float*       __restrict__ out)
{
    const int blk = blockIdx.x;    // b*NKV + kv
    const int b   = blk >> 3;
    const int kv  = blk & 7;
    const int tid = threadIdx.x;
    const int d   = tid & 127;
    const int gA  = tid >> 7;
    const int gB  = gA + 2;

    const int seq     = seq_lengths[b];
    const int n_pages = (seq + TPP - 1) / TPP;
    const int ns      = (n_pages < NSPLIT) ? n_pages : NSPLIT;

    const float* base0 = ws + (size_t)blk * NSPLIT * PART_F;

    float MA = -1e30f, MB = -1e30f;
    for (int si = 0; si < ns; ++si) {
        const float* p = base0 + si * PART_F;
        MA = fmaxf(MA, p[GQ * DH + gA]);
        MB = fmaxf(MB, p[GQ * DH + gB]);
    }

    float LA = 0.f, LB = 0.f, oA = 0.f, oB = 0.f;
    for (int si = 0; si < ns; ++si) {
        const float* p = base0 + si * PART_F;
        const float eA = __expf(p[GQ * DH + gA] - MA);
        const float eB = __expf(p[GQ * DH + gB] - MB);
        LA += p[GQ * DH + GQ + gA] * eA;
        LB += p[GQ * DH + GQ + gB] * eB;
        oA += p[gA * DH + d] * eA;
        oB += p[gB * DH + d] * eB;
    }

    float* ob = out + (size_t)(b * NQ + kv * GQ) * DH;
    ob[gA * DH + d] = oA / LA;
    ob[gB * DH + d] = oB / LB;
}

// ---------------------------------------------------------------------------
extern "C" void kernel_launch(void* const* d_in, const int* in_sizes, int n_in,
                              void* d_out, int out_size, void* d_ws, size_t ws_size,
                              hipStream_t stream)
{
    const float* query       = (const float*)d_in[0];
    const float* key_pages   = (const float*)d_in[1];
    const float* value_pages = (const float*)d_in[2];
    const int*   page_map    = (const int*)d_in[3];
    const int*   seq_lengths = (const int*)d_in[4];
    float*       out         = (float*)d_out;
    float*       ws          = (float*)d_ws;

    // ws usage: NBK*NSPLIT * PART_F floats = 4096 * 520 * 4B ~= 8.5 MB
    pa_partial<<<NBK * NSPLIT, 256, 0, stream>>>(
        query, key_pages, value_pages, page_map, seq_lengths, ws);
    pa_combine<<<NBK, 256, 0, stream>>>(ws, seq_lengths, out);
}

// Round 9
// 56.132 us; speedup vs baseline: 11.1933x; 1.1258x over previous
//
#include <hip/hip_runtime.h>
#include <math.h>

// Problem constants (from reference setup_inputs)
#define NB      32      // batch
#define NKV     8       // kv heads
#define NQ      32      // query heads
#define GQ      4       // GQA group size = NQ/NKV
#define DH      128     // head dim
#define TPP     16      // tokens per page
#define PPS     128     // pages per slot
#define NPAGES  4096    // total pages
#define NSPLIT  16      // S-splits per (b,kv)
#define NBK     (NB*NKV)        // 256 (b,kv) pairs
#define PAGE_F  (TPP*DH)        // floats per page = 2048
#define PART_F  (GQ*DH + 2*GQ)  // partial size: o[4][128] + m[4] + l[4] = 520
#define LOG2E   1.44269504088896340736f
#define DEFER_THR 8.0f          // log2-domain defer-max threshold (T13)

#if __has_builtin(__builtin_amdgcn_exp2f)
#define EXP2(x) __builtin_amdgcn_exp2f(x)
#else
#define EXP2(x) exp2f(x)
#endif

// ---- 16-lane all-reduce sum on the VALU pipe via DPP (no LDS swizzles) ----
// quad_perm(1,0,3,2)=0xB1, quad_perm(2,3,0,1)=0x4E,
// ROW_HALF_MIRROR=0x141, ROW_MIRROR=0x140 — all row-local (16 lanes).
template<int CTRL>
__device__ __forceinline__ float dpp_addf(float x) {
    int y = __builtin_amdgcn_update_dpp(0, __float_as_int(x), CTRL, 0xF, 0xF, true);
    return x + __int_as_float(y);
}
__device__ __forceinline__ float sum16(float x) {
    x = dpp_addf<0xB1>(x);    // pair swap
    x = dpp_addf<0x4E>(x);    // pair-of-pairs swap
    x = dpp_addf<0x141>(x);   // half mirror (cross-quad within 8)
    x = dpp_addf<0x140>(x);   // mirror (cross-8 within 16)
    return x;                 // uniform across the 16-lane row
}

// ---------------------------------------------------------------------------
// Kernel 1: barrier-free streaming paged attention partial (R5 structure).
// Each 16-lane group owns token slot `grp` of pages p = sp, sp+NSPLIT, ...
// with in-register online softmax in the exp2 domain + defer-max rescale.
// K/V stream global->register with 1-page data + 2-page index prefetch.
// ---------------------------------------------------------------------------
__global__ __launch_bounds__(256) void pa_partial(
    const float* __restrict__ query,
    const float* __restrict__ key_pages,
    const float* __restrict__ value_pages,
    const int*   __restrict__ page_map,
    const int*   __restrict__ seq_lengths,
    float*       __restrict__ ws)
{
    const int blk = blockIdx.x;          // (b*NKV + kv)*NSPLIT + sp
    const int sp  = blk & (NSPLIT - 1);
    const int bk  = blk >> 4;            // NSPLIT = 16
    const int kv  = bk & (NKV - 1);
    const int b   = bk >> 3;
    const int tid = threadIdx.x;

    const int seq     = seq_lengths[b];
    const int n_pages = (seq + TPP - 1) / TPP;
    if (sp >= n_pages) return;           // combine kernel skips inactive splits

    const int grp = tid >> 4;            // token slot 0..15 within a page
    const int l16 = tid & 15;            // lane within token group
    const int c0  = l16 * 4;             // chunk 0: floats [c0, c0+4)
    const int c1  = 64 + l16 * 4;        // chunk 1: floats [c1, c1+4)

    // Q fragments, PRE-SCALED by log2e so scores land in the exp2 domain
    float qreg[GQ][8];
    #pragma unroll
    for (int g = 0; g < GQ; ++g) {
        const float* qb = query + (size_t)((b * NQ + kv * GQ + g) * DH);
        const float4 a = *(const float4*)(qb + c0);
        const float4 c = *(const float4*)(qb + c1);
        qreg[g][0] = a.x * LOG2E; qreg[g][1] = a.y * LOG2E;
        qreg[g][2] = a.z * LOG2E; qreg[g][3] = a.w * LOG2E;
        qreg[g][4] = c.x * LOG2E; qreg[g][5] = c.y * LOG2E;
        qreg[g][6] = c.z * LOG2E; qreg[g][7] = c.w * LOG2E;
    }

    const float* kbase = key_pages   + (size_t)kv * NPAGES * PAGE_F;
    const float* vbase = value_pages + (size_t)kv * NPAGES * PAGE_F;
    const int*   pmap  = page_map + b * PPS;

    // online softmax state in log2 domain (finite init; masked tokens poison
    // to -inf so exp2(-inf - m) = 0 and defer-max never takes garbage)
    float m[GQ] = {-1e30f, -1e30f, -1e30f, -1e30f};
    float l[GQ] = {0.f, 0.f, 0.f, 0.f};
    float acc[GQ][8] = {};

    // page-index prefetch (2 ahead) + data prefetch (1 ahead)
    int pg_nxt = (sp + NSPLIT < n_pages) ? pmap[sp + NSPLIT] : 0;
    float4 ck0, ck1, cv0, cv1;
    {
        const size_t ro = (size_t)pmap[sp] * PAGE_F + grp * DH;
        ck0 = *(const float4*)(kbase + ro + c0);
        ck1 = *(const float4*)(kbase + ro + c1);
        cv0 = *(const float4*)(vbase + ro + c0);
        cv1 = *(const float4*)(vbase + ro + c1);
    }

    for (int p = sp; p < n_pages; p += NSPLIT) {
        // issue next page's loads first; index was prefetched last iteration
        float4 nk0, nk1, nv0, nv1;
        const int pn = p + NSPLIT;
        if (pn < n_pages) {
            const size_t ro = (size_t)pg_nxt * PAGE_F + grp * DH;
            nk0 = *(const float4*)(kbase + ro + c0);
            nk1 = *(const float4*)(kbase + ro + c1);
            nv0 = *(const float4*)(vbase + ro + c0);
            nv1 = *(const float4*)(vbase + ro + c1);
            pg_nxt = (pn + NSPLIT < n_pages) ? pmap[pn + NSPLIT] : 0;
        }

        const bool valid = (p * TPP + grp) < seq;
        const float kx[8] = {ck0.x, ck0.y, ck0.z, ck0.w, ck1.x, ck1.y, ck1.z, ck1.w};
        const float vx[8] = {cv0.x, cv0.y, cv0.z, cv0.w, cv1.x, cv1.y, cv1.z, cv1.w};

        #pragma unroll
        for (int g = 0; g < GQ; ++g) {
            // score (log2 domain): q[g].K reduced across 16 lanes on VALU/DPP
            float t = qreg[g][0]*kx[0] + qreg[g][1]*kx[1] + qreg[g][2]*kx[2] + qreg[g][3]*kx[3]
                    + qreg[g][4]*kx[4] + qreg[g][5]*kx[5] + qreg[g][6]*kx[6] + qreg[g][7]*kx[7];
            float s2 = sum16(t);
            s2 = valid ? s2 : -INFINITY;    // poison masked tokens

            // defer-max: rescale only when the max grows by > THR (rare;
            // wave-uniform branch, group-uniform predicate)
            const bool need = s2 > m[g] + DEFER_THR;
            if (__any(need)) {
                const float mn = need ? s2 : m[g];
                const float sc = EXP2(m[g] - mn);   // ==1 where !need
                m[g] = mn;
                l[g] *= sc;
                #pragma unroll
                for (int j = 0; j < 8; ++j) acc[g][j] *= sc;
            }
            const float pc = EXP2(s2 - m[g]);       // bounded by 2^THR; 0 if masked
            l[g] += pc;
            #pragma unroll
            for (int j = 0; j < 8; ++j) acc[g][j] += pc * vx[j];
        }

        ck0 = nk0; ck1 = nk1; cv0 = nv0; cv1 = nv1;   // SSA rename, free
    }

    // ---- block-level merge of the 16 group partials via LDS (R5 epilogue) ----
    __shared__ float s_acc[16][GQ][DH];   // 32 KB
    __shared__ float s_m[16][GQ];
    __shared__ float s_l[16][GQ];

    #pragma unroll
    for (int g = 0; g < GQ; ++g) {
        *(float4*)&s_acc[grp][g][c0] = make_float4(acc[g][0], acc[g][1], acc[g][2], acc[g][3]);
        *(float4*)&s_acc[grp][g][c1] = make_float4(acc[g][4], acc[g][5], acc[g][6], acc[g][7]);
    }
    if (l16 == 0) {
        #pragma unroll
        for (int g = 0; g < GQ; ++g) { s_m[grp][g] = m[g]; s_l[grp][g] = l[g]; }
    }
    __syncthreads();

    // remap: thread -> (gA, d) and (gB, d)
    const int d  = tid & 127;
    const int gA = tid >> 7;     // 0 or 1
    const int gB = gA + 2;       // 2 or 3

    float MA = -1e30f, MB = -1e30f;
    #pragma unroll
    for (int i = 0; i < 16; ++i) {
        MA = fmaxf(MA, s_m[i][gA]);
        MB = fmaxf(MB, s_m[i][gB]);
    }
    float LA = 0.f, LB = 0.f, oA = 0.f, oB = 0.f;
    #pragma unroll
    for (int i = 0; i < 16; ++i) {
        const float eA = EXP2(s_m[i][gA] - MA);
        const float eB = EXP2(s_m[i][gB] - MB);
        LA += s_l[i][gA] * eA;
        LB += s_l[i][gB] * eB;
        oA += s_acc[i][gA][d] * eA;
        oB += s_acc[i][gB][d] * eB;
    }

    // ---- write partial (o unnormalized, m, l in log2 domain) ----
    float* base = ws + (size_t)(bk * NSPLIT + sp) * PART_F;
    base[gA * DH + d] = oA;
    base[gB * DH + d] = oB;
    if (d == 0) {  // tid 0 writes g0,g2 ; tid 128 writes g1,g3
        base[GQ * DH + gA]      = MA;
        base[GQ * DH + GQ + gA] = LA;
        base[GQ * DH + gB]      = MB;
        base[GQ * DH + GQ + gB] = LB;
    }
}

// ---------------------------------------------------------------------------
// Kernel 2: combine the <=NSPLIT split partials per (b, kv), write output.
// (m, l are in the log2 domain -> merge weights via exp2.)
// ---------------------------------------------------------------------------
__global__ __launch_bounds__(256) void pa_combine(
    const float* __restrict__ ws,
    const int*   __restrict__ seq_lengths,
    float*       __restrict__ out)
{
    const int blk = blockIdx.x;    // b*NKV + kv
    const int b   = blk >> 3;
    const int kv  = blk & 7;
    const int tid = threadIdx.x;
    const int d   = tid & 127;
    const int gA  = tid >> 7;
    const int gB  = gA + 2;

    const int seq     = seq_lengths[b];
    const int n_pages = (seq + TPP - 1) / TPP;
    const int ns      = (n_pages < NSPLIT) ? n_pages : NSPLIT;

    const float* base0 = ws + (size_t)blk * NSPLIT * PART_F;

    float MA = -1e30f, MB = -1e30f;
    for (int si = 0; si < ns; ++si) {
        const float* p = base0 + si * PART_F;
        MA = fmaxf(MA, p[GQ * DH + gA]);
        MB = fmaxf(MB, p[GQ * DH + gB]);
    }

    float LA = 0.f, LB = 0.f, oA = 0.f, oB = 0.f;
    for (int si = 0; si < ns; ++si) {
        const float* p = base0 + si * PART_F;
        const float eA = EXP2(p[GQ * DH + gA] - MA);
        const float eB = EXP2(p[GQ * DH + gB] - MB);
        LA += p[GQ * DH + GQ + gA] * eA;
        LB += p[GQ * DH + GQ + gB] * eB;
        oA += p[gA * DH + d] * eA;
        oB += p[gB * DH + d] * eB;
    }

    float* ob = out + (size_t)(b * NQ + kv * GQ) * DH;
    ob[gA * DH + d] = oA / LA;
    ob[gB * DH + d] = oB / LB;
}

// ---------------------------------------------------------------------------
extern "C" void kernel_launch(void* const* d_in, const int* in_sizes, int n_in,
                              void* d_out, int out_size, void* d_ws, size_t ws_size,
                              hipStream_t stream)
{
    const float* query       = (const float*)d_in[0];
    const float* key_pages   = (const float*)d_in[1];
    const float* value_pages = (const float*)d_in[2];
    const int*   page_map    = (const int*)d_in[3];
    const int*   seq_lengths = (const int*)d_in[4];
    float*       out         = (float*)d_out;
    float*       ws          = (float*)d_ws;

    // ws usage: NBK*NSPLIT * PART_F floats = 4096 * 520 * 4B ~= 8.5 MB
    pa_partial<<<NBK * NSPLIT, 256, 0, stream>>>(
        query, key_pages, value_pages, page_map, seq_lengths, ws);
    pa_combine<<<NBK, 256, 0, stream>>>(ws, seq_lengths, out);
}

// Round 10
// 53.051 us; speedup vs baseline: 11.8434x; 1.0581x over previous
//
#include <hip/hip_runtime.h>
#include <math.h>

// Problem constants (from reference setup_inputs)
#define NB      32      // batch
#define NKV     8       // kv heads
#define NQ      32      // query heads
#define GQ      4       // GQA group size = NQ/NKV
#define DH      128     // head dim
#define TPP     16      // tokens per page
#define PPS     128     // pages per slot
#define NPAGES  4096    // total pages
#define NSPLIT  8       // S-splits per (b,kv)  (R9: 16 -> 8, amortize fixed costs)
#define NBK     (NB*NKV)        // 256 (b,kv) pairs
#define PAGE_F  (TPP*DH)        // floats per page = 2048
#define PART_F  (GQ*DH + 2*GQ)  // partial size: o[4][128] + m[4] + l[4] = 520
#define LOG2E   1.44269504088896340736f
#define DEFER_THR 8.0f          // log2-domain defer-max threshold (T13)

#if __has_builtin(__builtin_amdgcn_exp2f)
#define EXP2(x) __builtin_amdgcn_exp2f(x)
#else
#define EXP2(x) exp2f(x)
#endif

// ---- 16-lane all-reduce sum on the VALU pipe via DPP (no LDS swizzles) ----
template<int CTRL>
__device__ __forceinline__ float dpp_addf(float x) {
    int y = __builtin_amdgcn_update_dpp(0, __float_as_int(x), CTRL, 0xF, 0xF, true);
    return x + __int_as_float(y);
}
__device__ __forceinline__ float sum16(float x) {
    x = dpp_addf<0xB1>(x);    // quad_perm(1,0,3,2)
    x = dpp_addf<0x4E>(x);    // quad_perm(2,3,0,1)
    x = dpp_addf<0x141>(x);   // ROW_HALF_MIRROR
    x = dpp_addf<0x140>(x);   // ROW_MIRROR
    return x;                 // uniform across the 16-lane row
}

// ---------------------------------------------------------------------------
// Kernel 1: barrier-free streaming paged attention partial.
// Each 16-lane group owns token slot `grp` of pages p = sp, sp+NSPLIT, ...
// with in-register online softmax in the exp2 domain + defer-max rescale.
// K/V stream global->register with 1-page data + 2-page index prefetch.
// ---------------------------------------------------------------------------
__global__ __launch_bounds__(256) void pa_partial(
    const float* __restrict__ query,
    const float* __restrict__ key_pages,
    const float* __restrict__ value_pages,
    const int*   __restrict__ page_map,
    const int*   __restrict__ seq_lengths,
    float*       __restrict__ ws)
{
    const int blk = blockIdx.x;          // (b*NKV + kv)*NSPLIT + sp
    const int sp  = blk & (NSPLIT - 1);
    const int bk  = blk >> 3;            // NSPLIT = 8
    const int kv  = bk & (NKV - 1);
    const int b   = bk >> 3;
    const int tid = threadIdx.x;

    const int seq     = seq_lengths[b];
    const int n_pages = (seq + TPP - 1) / TPP;
    if (sp >= n_pages) return;           // combine kernel skips inactive splits

    const int grp = tid >> 4;            // token slot 0..15 within a page
    const int l16 = tid & 15;            // lane within token group
    const int c0  = l16 * 4;             // chunk 0: floats [c0, c0+4)
    const int c1  = 64 + l16 * 4;        // chunk 1: floats [c1, c1+4)

    // Q fragments, PRE-SCALED by log2e so scores land in the exp2 domain
    float qreg[GQ][8];
    #pragma unroll
    for (int g = 0; g < GQ; ++g) {
        const float* qb = query + (size_t)((b * NQ + kv * GQ + g) * DH);
        const float4 a = *(const float4*)(qb + c0);
        const float4 c = *(const float4*)(qb + c1);
        qreg[g][0] = a.x * LOG2E; qreg[g][1] = a.y * LOG2E;
        qreg[g][2] = a.z * LOG2E; qreg[g][3] = a.w * LOG2E;
        qreg[g][4] = c.x * LOG2E; qreg[g][5] = c.y * LOG2E;
        qreg[g][6] = c.z * LOG2E; qreg[g][7] = c.w * LOG2E;
    }

    const float* kbase = key_pages   + (size_t)kv * NPAGES * PAGE_F;
    const float* vbase = value_pages + (size_t)kv * NPAGES * PAGE_F;
    const int*   pmap  = page_map + b * PPS;

    // online softmax state in log2 domain (finite init; masked tokens poison
    // to -inf so exp2(-inf - m) = 0 and defer-max never takes garbage)
    float m[GQ] = {-1e30f, -1e30f, -1e30f, -1e30f};
    float l[GQ] = {0.f, 0.f, 0.f, 0.f};
    float acc[GQ][8] = {};

    // page-index prefetch (2 ahead) + data prefetch (1 ahead)
    int pg_nxt = (sp + NSPLIT < n_pages) ? pmap[sp + NSPLIT] : 0;
    float4 ck0, ck1, cv0, cv1;
    {
        const size_t ro = (size_t)pmap[sp] * PAGE_F + grp * DH;
        ck0 = *(const float4*)(kbase + ro + c0);
        ck1 = *(const float4*)(kbase + ro + c1);
        cv0 = *(const float4*)(vbase + ro + c0);
        cv1 = *(const float4*)(vbase + ro + c1);
    }

    for (int p = sp; p < n_pages; p += NSPLIT) {
        // issue next page's loads first; index was prefetched last iteration
        float4 nk0, nk1, nv0, nv1;
        const int pn = p + NSPLIT;
        if (pn < n_pages) {
            const size_t ro = (size_t)pg_nxt * PAGE_F + grp * DH;
            nk0 = *(const float4*)(kbase + ro + c0);
            nk1 = *(const float4*)(kbase + ro + c1);
            nv0 = *(const float4*)(vbase + ro + c0);
            nv1 = *(const float4*)(vbase + ro + c1);
            pg_nxt = (pn + NSPLIT < n_pages) ? pmap[pn + NSPLIT] : 0;
        }

        const bool valid = (p * TPP + grp) < seq;
        const float kx[8] = {ck0.x, ck0.y, ck0.z, ck0.w, ck1.x, ck1.y, ck1.z, ck1.w};
        const float vx[8] = {cv0.x, cv0.y, cv0.z, cv0.w, cv1.x, cv1.y, cv1.z, cv1.w};

        #pragma unroll
        for (int g = 0; g < GQ; ++g) {
            // score (log2 domain): q[g].K reduced across 16 lanes on VALU/DPP
            float t = qreg[g][0]*kx[0] + qreg[g][1]*kx[1] + qreg[g][2]*kx[2] + qreg[g][3]*kx[3]
                    + qreg[g][4]*kx[4] + qreg[g][5]*kx[5] + qreg[g][6]*kx[6] + qreg[g][7]*kx[7];
            float s2 = sum16(t);
            s2 = valid ? s2 : -INFINITY;    // poison masked tokens

            // defer-max: rescale only when the max grows by > THR
            const bool need = s2 > m[g] + DEFER_THR;
            if (__any(need)) {
                const float mn = need ? s2 : m[g];
                const float sc = EXP2(m[g] - mn);   // ==1 where !need
                m[g] = mn;
                l[g] *= sc;
                #pragma unroll
                for (int j = 0; j < 8; ++j) acc[g][j] *= sc;
            }
            const float pc = EXP2(s2 - m[g]);       // bounded by 2^THR; 0 if masked
            l[g] += pc;
            #pragma unroll
            for (int j = 0; j < 8; ++j) acc[g][j] += pc * vx[j];
        }

        ck0 = nk0; ck1 = nk1; cv0 = nv0; cv1 = nv1;   // SSA rename, free
    }

    // ---- block-level merge of the 16 group partials via LDS ----
    __shared__ float s_acc[16][GQ][DH];   // 32 KB
    __shared__ float s_m[16][GQ];
    __shared__ float s_l[16][GQ];

    #pragma unroll
    for (int g = 0; g < GQ; ++g) {
        *(float4*)&s_acc[grp][g][c0] = make_float4(acc[g][0], acc[g][1], acc[g][2], acc[g][3]);
        *(float4*)&s_acc[grp][g][c1] = make_float4(acc[g][4], acc[g][5], acc[g][6], acc[g][7]);
    }
    if (l16 == 0) {
        #pragma unroll
        for (int g = 0; g < GQ; ++g) { s_m[grp][g] = m[g]; s_l[grp][g] = l[g]; }
    }
    __syncthreads();

    // remap: thread -> (gA, d) and (gB, d)
    const int d  = tid & 127;
    const int gA = tid >> 7;     // 0 or 1
    const int gB = gA + 2;       // 2 or 3

    float MA = -1e30f, MB = -1e30f;
    #pragma unroll
    for (int i = 0; i < 16; ++i) {
        MA = fmaxf(MA, s_m[i][gA]);
        MB = fmaxf(MB, s_m[i][gB]);
    }
    float LA = 0.f, LB = 0.f, oA = 0.f, oB = 0.f;
    #pragma unroll
    for (int i = 0; i < 16; ++i) {
        const float eA = EXP2(s_m[i][gA] - MA);
        const float eB = EXP2(s_m[i][gB] - MB);
        LA += s_l[i][gA] * eA;
        LB += s_l[i][gB] * eB;
        oA += s_acc[i][gA][d] * eA;
        oB += s_acc[i][gB][d] * eB;
    }

    // ---- write partial (o unnormalized, m, l in log2 domain) ----
    float* base = ws + (size_t)(bk * NSPLIT + sp) * PART_F;
    base[gA * DH + d] = oA;
    base[gB * DH + d] = oB;
    if (d == 0) {  // tid 0 writes g0,g2 ; tid 128 writes g1,g3
        base[GQ * DH + gA]      = MA;
        base[GQ * DH + GQ + gA] = LA;
        base[GQ * DH + gB]      = MB;
        base[GQ * DH + GQ + gB] = LB;
    }
}

// ---------------------------------------------------------------------------
// Kernel 2: combine the <=NSPLIT split partials per (b, kv), write output.
// (m, l are in the log2 domain -> merge weights via exp2.)
// ---------------------------------------------------------------------------
__global__ __launch_bounds__(256) void pa_combine(
    const float* __restrict__ ws,
    const int*   __restrict__ seq_lengths,
    float*       __restrict__ out)
{
    const int blk = blockIdx.x;    // b*NKV + kv
    const int b   = blk >> 3;
    const int kv  = blk & 7;
    const int tid = threadIdx.x;
    const int d   = tid & 127;
    const int gA  = tid >> 7;
    const int gB  = gA + 2;

    const int seq     = seq_lengths[b];
    const int n_pages = (seq + TPP - 1) / TPP;
    const int ns      = (n_pages < NSPLIT) ? n_pages : NSPLIT;

    const float* base0 = ws + (size_t)blk * NSPLIT * PART_F;

    float MA = -1e30f, MB = -1e30f;
    for (int si = 0; si < ns; ++si) {
        const float* p = base0 + si * PART_F;
        MA = fmaxf(MA, p[GQ * DH + gA]);
        MB = fmaxf(MB, p[GQ * DH + gB]);
    }

    float LA = 0.f, LB = 0.f, oA = 0.f, oB = 0.f;
    for (int si = 0; si < ns; ++si) {
        const float* p = base0 + si * PART_F;
        const float eA = EXP2(p[GQ * DH + gA] - MA);
        const float eB = EXP2(p[GQ * DH + gB] - MB);
        LA += p[GQ * DH + GQ + gA] * eA;
        LB += p[GQ * DH + GQ + gB] * eB;
        oA += p[gA * DH + d] * eA;
        oB += p[gB * DH + d] * eB;
    }

    float* ob = out + (size_t)(b * NQ + kv * GQ) * DH;
    ob[gA * DH + d] = oA / LA;
    ob[gB * DH + d] = oB / LB;
}

// ---------------------------------------------------------------------------
extern "C" void kernel_launch(void* const* d_in, const int* in_sizes, int n_in,
                              void* d_out, int out_size, void* d_ws, size_t ws_size,
                              hipStream_t stream)
{
    const float* query       = (const float*)d_in[0];
    const float* key_pages   = (const float*)d_in[1];
    const float* value_pages = (const float*)d_in[2];
    const int*   page_map    = (const int*)d_in[3];
    const int*   seq_lengths = (const int*)d_in[4];
    float*       out         = (float*)d_out;
    float*       ws          = (float*)d_ws;

    // ws usage: NBK*NSPLIT * PART_F floats = 2048 * 520 * 4B ~= 4.3 MB
    pa_partial<<<NBK * NSPLIT, 256, 0, stream>>>(
        query, key_pages, value_pages, page_map, seq_lengths, ws);
    pa_combine<<<NBK, 256, 0, stream>>>(ws, seq_lengths, out);
}

// Round 11
// 52.818 us; speedup vs baseline: 11.8956x; 1.0044x over previous
//
#include <hip/hip_runtime.h>
#include <math.h>

// Problem constants (from reference setup_inputs)
#define NB      32      // batch
#define NKV     8       // kv heads
#define NQ      32      // query heads
#define GQ      4       // GQA group size = NQ/NKV
#define DH      128     // head dim
#define TPP     16      // tokens per page
#define PPS     128     // pages per slot
#define NPAGES  4096    // total pages
#define NSPLIT  4       // S-splits per (b,kv)  (R10: 8 -> 4, amortize fixed costs)
#define NBK     (NB*NKV)        // 256 (b,kv) pairs
#define PAGE_F  (TPP*DH)        // floats per page = 2048
#define PART_F  (GQ*DH + 2*GQ)  // partial size: o[4][128] + m[4] + l[4] = 520
#define LOG2E   1.44269504088896340736f
#define DEFER_THR 8.0f          // log2-domain defer-max threshold (T13)

#if __has_builtin(__builtin_amdgcn_exp2f)
#define EXP2(x) __builtin_amdgcn_exp2f(x)
#else
#define EXP2(x) exp2f(x)
#endif

// ---- 16-lane all-reduce sum on the VALU pipe via DPP (no LDS swizzles) ----
template<int CTRL>
__device__ __forceinline__ float dpp_addf(float x) {
    int y = __builtin_amdgcn_update_dpp(0, __float_as_int(x), CTRL, 0xF, 0xF, true);
    return x + __int_as_float(y);
}
__device__ __forceinline__ float sum16(float x) {
    x = dpp_addf<0xB1>(x);    // quad_perm(1,0,3,2)
    x = dpp_addf<0x4E>(x);    // quad_perm(2,3,0,1)
    x = dpp_addf<0x141>(x);   // ROW_HALF_MIRROR
    x = dpp_addf<0x140>(x);   // ROW_MIRROR
    return x;                 // uniform across the 16-lane row
}

// ---------------------------------------------------------------------------
// Kernel 1: barrier-free streaming paged attention partial.
// Each 16-lane group owns token slot `grp` of pages p = sp, sp+NSPLIT, ...
// with in-register online softmax in the exp2 domain + defer-max rescale.
// K/V stream global->register with 1-page data + 2-page index prefetch.
// ---------------------------------------------------------------------------
__global__ __launch_bounds__(256) void pa_partial(
    const float* __restrict__ query,
    const float* __restrict__ key_pages,
    const float* __restrict__ value_pages,
    const int*   __restrict__ page_map,
    const int*   __restrict__ seq_lengths,
    float*       __restrict__ ws)
{
    const int blk = blockIdx.x;          // (b*NKV + kv)*NSPLIT + sp
    const int sp  = blk & (NSPLIT - 1);
    const int bk  = blk >> 2;            // NSPLIT = 4
    const int kv  = bk & (NKV - 1);
    const int b   = bk >> 3;
    const int tid = threadIdx.x;

    const int seq     = seq_lengths[b];
    const int n_pages = (seq + TPP - 1) / TPP;
    if (sp >= n_pages) return;           // combine kernel skips inactive splits

    const int grp = tid >> 4;            // token slot 0..15 within a page
    const int l16 = tid & 15;            // lane within token group
    const int c0  = l16 * 4;             // chunk 0: floats [c0, c0+4)
    const int c1  = 64 + l16 * 4;        // chunk 1: floats [c1, c1+4)

    // Q fragments, PRE-SCALED by log2e so scores land in the exp2 domain
    float qreg[GQ][8];
    #pragma unroll
    for (int g = 0; g < GQ; ++g) {
        const float* qb = query + (size_t)((b * NQ + kv * GQ + g) * DH);
        const float4 a = *(const float4*)(qb + c0);
        const float4 c = *(const float4*)(qb + c1);
        qreg[g][0] = a.x * LOG2E; qreg[g][1] = a.y * LOG2E;
        qreg[g][2] = a.z * LOG2E; qreg[g][3] = a.w * LOG2E;
        qreg[g][4] = c.x * LOG2E; qreg[g][5] = c.y * LOG2E;
        qreg[g][6] = c.z * LOG2E; qreg[g][7] = c.w * LOG2E;
    }

    const float* kbase = key_pages   + (size_t)kv * NPAGES * PAGE_F;
    const float* vbase = value_pages + (size_t)kv * NPAGES * PAGE_F;
    const int*   pmap  = page_map + b * PPS;

    // online softmax state in log2 domain (finite init; masked tokens poison
    // to -inf so exp2(-inf - m) = 0 and defer-max never takes garbage)
    float m[GQ] = {-1e30f, -1e30f, -1e30f, -1e30f};
    float l[GQ] = {0.f, 0.f, 0.f, 0.f};
    float acc[GQ][8] = {};

    // page-index prefetch (2 ahead) + data prefetch (1 ahead)
    int pg_nxt = (sp + NSPLIT < n_pages) ? pmap[sp + NSPLIT] : 0;
    float4 ck0, ck1, cv0, cv1;
    {
        const size_t ro = (size_t)pmap[sp] * PAGE_F + grp * DH;
        ck0 = *(const float4*)(kbase + ro + c0);
        ck1 = *(const float4*)(kbase + ro + c1);
        cv0 = *(const float4*)(vbase + ro + c0);
        cv1 = *(const float4*)(vbase + ro + c1);
    }

    for (int p = sp; p < n_pages; p += NSPLIT) {
        // issue next page's loads first; index was prefetched last iteration
        float4 nk0, nk1, nv0, nv1;
        const int pn = p + NSPLIT;
        if (pn < n_pages) {
            const size_t ro = (size_t)pg_nxt * PAGE_F + grp * DH;
            nk0 = *(const float4*)(kbase + ro + c0);
            nk1 = *(const float4*)(kbase + ro + c1);
            nv0 = *(const float4*)(vbase + ro + c0);
            nv1 = *(const float4*)(vbase + ro + c1);
            pg_nxt = (pn + NSPLIT < n_pages) ? pmap[pn + NSPLIT] : 0;
        }

        const bool valid = (p * TPP + grp) < seq;
        const float kx[8] = {ck0.x, ck0.y, ck0.z, ck0.w, ck1.x, ck1.y, ck1.z, ck1.w};
        const float vx[8] = {cv0.x, cv0.y, cv0.z, cv0.w, cv1.x, cv1.y, cv1.z, cv1.w};

        #pragma unroll
        for (int g = 0; g < GQ; ++g) {
            // score (log2 domain): q[g].K reduced across 16 lanes on VALU/DPP
            float t = qreg[g][0]*kx[0] + qreg[g][1]*kx[1] + qreg[g][2]*kx[2] + qreg[g][3]*kx[3]
                    + qreg[g][4]*kx[4] + qreg[g][5]*kx[5] + qreg[g][6]*kx[6] + qreg[g][7]*kx[7];
            float s2 = sum16(t);
            s2 = valid ? s2 : -INFINITY;    // poison masked tokens

            // defer-max: rescale only when the max grows by > THR
            const bool need = s2 > m[g] + DEFER_THR;
            if (__any(need)) {
                const float mn = need ? s2 : m[g];
                const float sc = EXP2(m[g] - mn);   // ==1 where !need
                m[g] = mn;
                l[g] *= sc;
                #pragma unroll
                for (int j = 0; j < 8; ++j) acc[g][j] *= sc;
            }
            const float pc = EXP2(s2 - m[g]);       // bounded by 2^THR; 0 if masked
            l[g] += pc;
            #pragma unroll
            for (int j = 0; j < 8; ++j) acc[g][j] += pc * vx[j];
        }

        ck0 = nk0; ck1 = nk1; cv0 = nv0; cv1 = nv1;   // SSA rename, free
    }

    // ---- block-level merge of the 16 group partials via LDS ----
    __shared__ float s_acc[16][GQ][DH];   // 32 KB
    __shared__ float s_m[16][GQ];
    __shared__ float s_l[16][GQ];

    #pragma unroll
    for (int g = 0; g < GQ; ++g) {
        *(float4*)&s_acc[grp][g][c0] = make_float4(acc[g][0], acc[g][1], acc[g][2], acc[g][3]);
        *(float4*)&s_acc[grp][g][c1] = make_float4(acc[g][4], acc[g][5], acc[g][6], acc[g][7]);
    }
    if (l16 == 0) {
        #pragma unroll
        for (int g = 0; g < GQ; ++g) { s_m[grp][g] = m[g]; s_l[grp][g] = l[g]; }
    }
    __syncthreads();

    // remap: thread -> (gA, d) and (gB, d)
    const int d  = tid & 127;
    const int gA = tid >> 7;     // 0 or 1
    const int gB = gA + 2;       // 2 or 3

    float MA = -1e30f, MB = -1e30f;
    #pragma unroll
    for (int i = 0; i < 16; ++i) {
        MA = fmaxf(MA, s_m[i][gA]);
        MB = fmaxf(MB, s_m[i][gB]);
    }
    float LA = 0.f, LB = 0.f, oA = 0.f, oB = 0.f;
    #pragma unroll
    for (int i = 0; i < 16; ++i) {
        const float eA = EXP2(s_m[i][gA] - MA);
        const float eB = EXP2(s_m[i][gB] - MB);
        LA += s_l[i][gA] * eA;
        LB += s_l[i][gB] * eB;
        oA += s_acc[i][gA][d] * eA;
        oB += s_acc[i][gB][d] * eB;
    }

    // ---- write partial (o unnormalized, m, l in log2 domain) ----
    float* base = ws + (size_t)(bk * NSPLIT + sp) * PART_F;
    base[gA * DH + d] = oA;
    base[gB * DH + d] = oB;
    if (d == 0) {  // tid 0 writes g0,g2 ; tid 128 writes g1,g3
        base[GQ * DH + gA]      = MA;
        base[GQ * DH + GQ + gA] = LA;
        base[GQ * DH + gB]      = MB;
        base[GQ * DH + GQ + gB] = LB;
    }
}

// ---------------------------------------------------------------------------
// Kernel 2: combine the <=NSPLIT split partials per (b, kv), write output.
// (m, l are in the log2 domain -> merge weights via exp2.)
// ---------------------------------------------------------------------------
__global__ __launch_bounds__(256) void pa_combine(
    const float* __restrict__ ws,
    const int*   __restrict__ seq_lengths,
    float*       __restrict__ out)
{
    const int blk = blockIdx.x;    // b*NKV + kv
    const int b   = blk >> 3;
    const int kv  = blk & 7;
    const int tid = threadIdx.x;
    const int d   = tid & 127;
    const int gA  = tid >> 7;
    const int gB  = gA + 2;

    const int seq     = seq_lengths[b];
    const int n_pages = (seq + TPP - 1) / TPP;
    const int ns      = (n_pages < NSPLIT) ? n_pages : NSPLIT;

    const float* base0 = ws + (size_t)blk * NSPLIT * PART_F;

    float MA = -1e30f, MB = -1e30f;
    for (int si = 0; si < ns; ++si) {
        const float* p = base0 + si * PART_F;
        MA = fmaxf(MA, p[GQ * DH + gA]);
        MB = fmaxf(MB, p[GQ * DH + gB]);
    }

    float LA = 0.f, LB = 0.f, oA = 0.f, oB = 0.f;
    for (int si = 0; si < ns; ++si) {
        const float* p = base0 + si * PART_F;
        const float eA = EXP2(p[GQ * DH + gA] - MA);
        const float eB = EXP2(p[GQ * DH + gB] - MB);
        LA += p[GQ * DH + GQ + gA] * eA;
        LB += p[GQ * DH + GQ + gB] * eB;
        oA += p[gA * DH + d] * eA;
        oB += p[gB * DH + d] * eB;
    }

    float* ob = out + (size_t)(b * NQ + kv * GQ) * DH;
    ob[gA * DH + d] = oA / LA;
    ob[gB * DH + d] = oB / LB;
}

// ---------------------------------------------------------------------------
extern "C" void kernel_launch(void* const* d_in, const int* in_sizes, int n_in,
                              void* d_out, int out_size, void* d_ws, size_t ws_size,
                              hipStream_t stream)
{
    const float* query       = (const float*)d_in[0];
    const float* key_pages   = (const float*)d_in[1];
    const float* value_pages = (const float*)d_in[2];
    const int*   page_map    = (const int*)d_in[3];
    const int*   seq_lengths = (const int*)d_in[4];
    float*       out         = (float*)d_out;
    float*       ws          = (float*)d_ws;

    // ws usage: NBK*NSPLIT * PART_F floats = 1024 * 520 * 4B ~= 2.1 MB
    pa_partial<<<NBK * NSPLIT, 256, 0, stream>>>(
        query, key_pages, value_pages, page_map, seq_lengths, ws);
    pa_combine<<<NBK, 256, 0, stream>>>(ws, seq_lengths, out);
}